// Round 11
// baseline (958.490 us; speedup 1.0000x reference)
//
#include <hip/hip_runtime.h>

#define BB 32
#define TT 128
#define II 256
#define HH 256
#define OO 128
#define FWID 512  // H + I

// d_ws: u64 slots[2][BB][HH] (parity, batch, row) = 128 KB.
// Slot = (stamp<<32)|float_bits(h); step s consumes stamp>=s from parity s&1,
// publishes stamp s+1 into parity (s+1)&1. All slot traffic agent-scope relaxed
// (no fences) -- protocol proven on HW in R2/R3/R5/R6/R8.
// Overwrite safety: producer writes stamp s+2 (same parity slot as stamp s)
// only in step s+1, gated on its gatherer's gather(s+1) = all rows at stamp
// s+1 = every block exited its stamp-s gather loop (all stamp-s reads done).
// LDS lh overwrite safety as proven in R6 header. u64 atomics cannot tear.
//
// R11 vs R6 (547 us regression) and R8 (258 us best): dedicated gatherer waves
// remove consume+U+P (~1700-2100 cy) from the poll re-arm path (R8's hidden
// cost), and the R6 congestion spiral (unthrottled polls -> ~12 iter/step ->
// ~10 TB/s on the 128 KB hot slot region -> latency inflation -> more polling)
// is broken by a s_sleep(4) rate cap (~1 poll/900 cy max, ~2.5/step expected).
// Gatherer waves run at s_setprio(2) so post-detect ds_write+flag cuts through
// compute-wave issue pressure.

typedef unsigned long long u64;

__device__ __forceinline__ u64 slot_ld(const u64* p) {
    return __hip_atomic_load(p, __ATOMIC_RELAXED, __HIP_MEMORY_SCOPE_AGENT);
}

// One wave gathers 256 rows of one batch (4 slots/lane), stages h to LDS,
// release-stores an LDS flag. Rate-capped poll: s_sleep(4) (~256 cy) between
// stale iterations bounds fabric pressure on the hot slot lines.
__device__ __forceinline__ void gather_to_lds(const u64* base, int lane, unsigned us,
                                              float* dst, int* flag, int fval) {
    const u64* p = base + 4 * lane;
    u64 a, b, c, d;
    for (;;) {
        a = slot_ld(p);
        b = slot_ld(p + 1);
        c = slot_ld(p + 2);
        d = slot_ld(p + 3);
        bool ok = ((unsigned)(a >> 32) >= us) & ((unsigned)(b >> 32) >= us) &
                  ((unsigned)(c >> 32) >= us) & ((unsigned)(d >> 32) >= us);
        if (__all(ok)) break;
        __builtin_amdgcn_s_sleep(4);   // rate cap: breaks the R6 poll-congestion spiral
    }
    float4 hv;
    hv.x = __uint_as_float((unsigned)a);
    hv.y = __uint_as_float((unsigned)b);
    hv.z = __uint_as_float((unsigned)c);
    hv.w = __uint_as_float((unsigned)d);
    *reinterpret_cast<float4*>(dst + 4 * lane) = hv;
    if (lane == 0)  // release drains the wave's ds_write before the flag
        __hip_atomic_store(flag, fval, __ATOMIC_RELEASE, __HIP_MEMORY_SCOPE_WORKGROUP);
}

__global__ __launch_bounds__(640, 1)
void stpn_kernel(const float* __restrict__ x,      // (B,T,I)
                 const float* __restrict__ wlam,   // (H,FWID)
                 const float* __restrict__ wgam,   // (H,FWID)
                 const float* __restrict__ w,      // (H,FWID)
                 const float* __restrict__ bias,   // (H)
                 const float* __restrict__ wout,   // (O,H)
                 const float* __restrict__ bout,   // (O)
                 float* __restrict__ out,          // tag(4096) | h_T(8192) | F_T
                 u64* __restrict__ slots)
{
    __shared__ __align__(16) float lh[2][2][HH];   // [A/B][parity][row]
    __shared__ int lflag[2][2];                    // [A/B][parity]

    const int tid  = threadIdx.x;
    const int bk   = blockIdx.x;
    const int pr   = bk & 15;        // batch pair: batches pr, pr+16
    const int sl   = bk >> 4;        // row slice 0..15
    const int bA   = pr, bB = pr + 16;

    if (tid < 4) ((int*)lflag)[tid] = 0;
    __syncthreads();                  // flag init visible to all 10 waves

    // ================= gatherer waves (tid 512..639) =================
    if (tid >= 512) {
        const int gi   = (tid >> 6) - 8;   // 0 -> batch A, 1 -> batch B
        const int lane = tid & 63;
        const int gb   = gi ? bB : bA;
        __builtin_amdgcn_s_setprio(2);     // win issue arbitration post-detect
        for (int s = 0; s < TT; ++s) {
            const int par = s & 1;
            gather_to_lds(slots + ((size_t)par * BB + gb) * HH, lane,
                          (unsigned)s, lh[gi][par], &lflag[gi][par], s + 1);
        }
        if (sl == 0) {  // final h (stamp TT) for tag_space; parity TT&1 == 0
            gather_to_lds(slots + ((size_t)(TT & 1) * BB + gb) * HH, lane,
                          (unsigned)TT, lh[gi][0], &lflag[gi][0], TT + 1);
        }
        return;
    }

    // ================= compute waves (tid 0..511) =================
    const int wv   = tid >> 6;       // 0..7
    const int lane = tid & 63;
    const int hw   = lane >> 5;
    const int i    = lane & 31;
    const int r    = sl * 16 + wv * 2 + hw;

    float4 W4[4], L4[4], G4[4], FA[4], FB[4];
    {
        const float4* wr = reinterpret_cast<const float4*>(w    + (size_t)r * FWID);
        const float4* lr = reinterpret_cast<const float4*>(wlam + (size_t)r * FWID);
        const float4* gr = reinterpret_cast<const float4*>(wgam + (size_t)r * FWID);
#pragma unroll
        for (int k = 0; k < 4; ++k) {
            W4[k] = wr[k * 32 + i];
            L4[k] = lr[k * 32 + i];
            G4[k] = gr[k * 32 + i];
            FA[k] = make_float4(0.f, 0.f, 0.f, 0.f);
            FB[k] = make_float4(0.f, 0.f, 0.f, 0.f);
        }
    }
    const float bj = bias[r];
    float hlA = 0.f, hlB = 0.f;

    for (int s = 0; s < TT; ++s) {
        const int par = s & 1;

        const float4* xA = reinterpret_cast<const float4*>(x + ((size_t)bA * TT + s) * II);
        const float4* xB = reinterpret_cast<const float4*>(x + ((size_t)bB * TT + s) * II);
        float4 TA0 = xA[i], TA1 = xA[32 + i];
        float4 TB0 = xB[i], TB1 = xB[32 + i];

        // ---- Phase P: independent of h(s) ----
        float4 twA2, twA3, twB2, twB3;
        float4 dxa = make_float4(0,0,0,0), na = make_float4(0,0,0,0);
        float4 dxb = make_float4(0,0,0,0), nb = make_float4(0,0,0,0);
        {
            float4 t;
            t.x = W4[0].x + FA[0].x; t.y = W4[0].y + FA[0].y; t.z = W4[0].z + FA[0].z; t.w = W4[0].w + FA[0].w;
            dxa.x = fmaf(TA0.x, t.x, dxa.x); dxa.y = fmaf(TA0.y, t.y, dxa.y);
            dxa.z = fmaf(TA0.z, t.z, dxa.z); dxa.w = fmaf(TA0.w, t.w, dxa.w);
            na.x = fmaf(t.x, t.x, na.x); na.y = fmaf(t.y, t.y, na.y);
            na.z = fmaf(t.z, t.z, na.z); na.w = fmaf(t.w, t.w, na.w);
            t.x = W4[1].x + FA[1].x; t.y = W4[1].y + FA[1].y; t.z = W4[1].z + FA[1].z; t.w = W4[1].w + FA[1].w;
            dxa.x = fmaf(TA1.x, t.x, dxa.x); dxa.y = fmaf(TA1.y, t.y, dxa.y);
            dxa.z = fmaf(TA1.z, t.z, dxa.z); dxa.w = fmaf(TA1.w, t.w, dxa.w);
            na.x = fmaf(t.x, t.x, na.x); na.y = fmaf(t.y, t.y, na.y);
            na.z = fmaf(t.z, t.z, na.z); na.w = fmaf(t.w, t.w, na.w);
            t.x = W4[0].x + FB[0].x; t.y = W4[0].y + FB[0].y; t.z = W4[0].z + FB[0].z; t.w = W4[0].w + FB[0].w;
            dxb.x = fmaf(TB0.x, t.x, dxb.x); dxb.y = fmaf(TB0.y, t.y, dxb.y);
            dxb.z = fmaf(TB0.z, t.z, dxb.z); dxb.w = fmaf(TB0.w, t.w, dxb.w);
            nb.x = fmaf(t.x, t.x, nb.x); nb.y = fmaf(t.y, t.y, nb.y);
            nb.z = fmaf(t.z, t.z, nb.z); nb.w = fmaf(t.w, t.w, nb.w);
            t.x = W4[1].x + FB[1].x; t.y = W4[1].y + FB[1].y; t.z = W4[1].z + FB[1].z; t.w = W4[1].w + FB[1].w;
            dxb.x = fmaf(TB1.x, t.x, dxb.x); dxb.y = fmaf(TB1.y, t.y, dxb.y);
            dxb.z = fmaf(TB1.z, t.z, dxb.z); dxb.w = fmaf(TB1.w, t.w, dxb.w);
            nb.x = fmaf(t.x, t.x, nb.x); nb.y = fmaf(t.y, t.y, nb.y);
            nb.z = fmaf(t.z, t.z, nb.z); nb.w = fmaf(t.w, t.w, nb.w);
            twA2.x = W4[2].x + FA[2].x; twA2.y = W4[2].y + FA[2].y; twA2.z = W4[2].z + FA[2].z; twA2.w = W4[2].w + FA[2].w;
            na.x = fmaf(twA2.x, twA2.x, na.x); na.y = fmaf(twA2.y, twA2.y, na.y);
            na.z = fmaf(twA2.z, twA2.z, na.z); na.w = fmaf(twA2.w, twA2.w, na.w);
            twA3.x = W4[3].x + FA[3].x; twA3.y = W4[3].y + FA[3].y; twA3.z = W4[3].z + FA[3].z; twA3.w = W4[3].w + FA[3].w;
            na.x = fmaf(twA3.x, twA3.x, na.x); na.y = fmaf(twA3.y, twA3.y, na.y);
            na.z = fmaf(twA3.z, twA3.z, na.z); na.w = fmaf(twA3.w, twA3.w, na.w);
            twB2.x = W4[2].x + FB[2].x; twB2.y = W4[2].y + FB[2].y; twB2.z = W4[2].z + FB[2].z; twB2.w = W4[2].w + FB[2].w;
            nb.x = fmaf(twB2.x, twB2.x, nb.x); nb.y = fmaf(twB2.y, twB2.y, nb.y);
            nb.z = fmaf(twB2.z, twB2.z, nb.z); nb.w = fmaf(twB2.w, twB2.w, nb.w);
            twB3.x = W4[3].x + FB[3].x; twB3.y = W4[3].y + FB[3].y; twB3.z = W4[3].z + FB[3].z; twB3.w = W4[3].w + FB[3].w;
            nb.x = fmaf(twB3.x, twB3.x, nb.x); nb.y = fmaf(twB3.y, twB3.y, nb.y);
            nb.z = fmaf(twB3.z, twB3.z, nb.z); nb.w = fmaf(twB3.w, twB3.w, nb.w);
        }
        float dxA = (dxa.x + dxa.y) + (dxa.z + dxa.w);
        float nrmA = (na.x + na.y) + (na.z + na.w);
        float dxB = (dxb.x + dxb.y) + (dxb.z + dxb.w);
        float nrmB = (nb.x + nb.y) + (nb.z + nb.w);
#pragma unroll
        for (int off = 1; off <= 16; off <<= 1) {
            dxA  += __shfl_xor(dxA,  off, 64);
            nrmA += __shfl_xor(nrmA, off, 64);
            dxB  += __shfl_xor(dxB,  off, 64);
            nrmB += __shfl_xor(nrmB, off, 64);
        }
        const float invnA = 1.0f / (sqrtf(nrmA) + 1e-16f);
        const float invnB = 1.0f / (sqrtf(nrmB) + 1e-16f);

#pragma unroll
        for (int k = 0; k < 4; ++k) {
            FA[k].x = L4[k].x * (FA[k].x * invnA); FA[k].y = L4[k].y * (FA[k].y * invnA);
            FA[k].z = L4[k].z * (FA[k].z * invnA); FA[k].w = L4[k].w * (FA[k].w * invnA);
            FB[k].x = L4[k].x * (FB[k].x * invnB); FB[k].y = L4[k].y * (FB[k].y * invnB);
            FB[k].z = L4[k].z * (FB[k].z * invnB); FB[k].w = L4[k].w * (FB[k].w * invnB);
        }
        TA0.x *= G4[0].x; TA0.y *= G4[0].y; TA0.z *= G4[0].z; TA0.w *= G4[0].w;
        TA1.x *= G4[1].x; TA1.y *= G4[1].y; TA1.z *= G4[1].z; TA1.w *= G4[1].w;
        TB0.x *= G4[0].x; TB0.y *= G4[0].y; TB0.z *= G4[0].z; TB0.w *= G4[0].w;
        TB1.x *= G4[1].x; TB1.y *= G4[1].y; TB1.z *= G4[1].z; TB1.w *= G4[1].w;

        // ---- batch A critical section ----
        while (__hip_atomic_load(&lflag[0][par], __ATOMIC_ACQUIRE, __HIP_MEMORY_SCOPE_WORKGROUP) <= s) {}
        const float4* lA4 = reinterpret_cast<const float4*>(lh[0][par]);
        float4 TA2 = lA4[i], TA3 = lA4[32 + i];
        float dhA = fmaf(TA2.x, twA2.x, fmaf(TA2.y, twA2.y, fmaf(TA2.z, twA2.z, TA2.w * twA2.w)));
        dhA = fmaf(TA3.x, twA3.x, fmaf(TA3.y, twA3.y, fmaf(TA3.z, twA3.z, fmaf(TA3.w, twA3.w, dhA))));
#pragma unroll
        for (int off = 1; off <= 16; off <<= 1) dhA += __shfl_xor(dhA, off, 64);
        const float eA = __expf(2.0f * (dxA + dhA + bj));
        const float hA = (1.0f - 2.0f / (eA + 1.0f)) * invnA;
        hlA = hA;
        if (i == 0) {
            __hip_atomic_store(slots + ((size_t)(par ^ 1) * BB + bA) * HH + r,
                               ((u64)(unsigned)(s + 1) << 32) | (unsigned)__float_as_uint(hA),
                               __ATOMIC_RELAXED, __HIP_MEMORY_SCOPE_AGENT);
        }

        // ---- batch B critical section ----
        while (__hip_atomic_load(&lflag[1][par], __ATOMIC_ACQUIRE, __HIP_MEMORY_SCOPE_WORKGROUP) <= s) {}
        const float4* lB4 = reinterpret_cast<const float4*>(lh[1][par]);
        float4 TB2 = lB4[i], TB3 = lB4[32 + i];
        float dhB = fmaf(TB2.x, twB2.x, fmaf(TB2.y, twB2.y, fmaf(TB2.z, twB2.z, TB2.w * twB2.w)));
        dhB = fmaf(TB3.x, twB3.x, fmaf(TB3.y, twB3.y, fmaf(TB3.z, twB3.z, fmaf(TB3.w, twB3.w, dhB))));
#pragma unroll
        for (int off = 1; off <= 16; off <<= 1) dhB += __shfl_xor(dhB, off, 64);
        const float eB = __expf(2.0f * (dxB + dhB + bj));
        const float hB = (1.0f - 2.0f / (eB + 1.0f)) * invnB;
        hlB = hB;
        if (i == 0) {
            __hip_atomic_store(slots + ((size_t)(par ^ 1) * BB + bB) * HH + r,
                               ((u64)(unsigned)(s + 1) << 32) | (unsigned)__float_as_uint(hB),
                               __ATOMIC_RELAXED, __HIP_MEMORY_SCOPE_AGENT);
        }

        // ---- Phase U: F += (gamma*t)*h ----
        FA[0].x = fmaf(TA0.x, hA, FA[0].x); FA[0].y = fmaf(TA0.y, hA, FA[0].y);
        FA[0].z = fmaf(TA0.z, hA, FA[0].z); FA[0].w = fmaf(TA0.w, hA, FA[0].w);
        FA[1].x = fmaf(TA1.x, hA, FA[1].x); FA[1].y = fmaf(TA1.y, hA, FA[1].y);
        FA[1].z = fmaf(TA1.z, hA, FA[1].z); FA[1].w = fmaf(TA1.w, hA, FA[1].w);
        FA[2].x = fmaf(G4[2].x * TA2.x, hA, FA[2].x); FA[2].y = fmaf(G4[2].y * TA2.y, hA, FA[2].y);
        FA[2].z = fmaf(G4[2].z * TA2.z, hA, FA[2].z); FA[2].w = fmaf(G4[2].w * TA2.w, hA, FA[2].w);
        FA[3].x = fmaf(G4[3].x * TA3.x, hA, FA[3].x); FA[3].y = fmaf(G4[3].y * TA3.y, hA, FA[3].y);
        FA[3].z = fmaf(G4[3].z * TA3.z, hA, FA[3].z); FA[3].w = fmaf(G4[3].w * TA3.w, hA, FA[3].w);
        FB[0].x = fmaf(TB0.x, hB, FB[0].x); FB[0].y = fmaf(TB0.y, hB, FB[0].y);
        FB[0].z = fmaf(TB0.z, hB, FB[0].z); FB[0].w = fmaf(TB0.w, hB, FB[0].w);
        FB[1].x = fmaf(TB1.x, hB, FB[1].x); FB[1].y = fmaf(TB1.y, hB, FB[1].y);
        FB[1].z = fmaf(TB1.z, hB, FB[1].z); FB[1].w = fmaf(TB1.w, hB, FB[1].w);
        FB[2].x = fmaf(G4[2].x * TB2.x, hB, FB[2].x); FB[2].y = fmaf(G4[2].y * TB2.y, hB, FB[2].y);
        FB[2].z = fmaf(G4[2].z * TB2.z, hB, FB[2].z); FB[2].w = fmaf(G4[2].w * TB2.w, hB, FB[2].w);
        FB[3].x = fmaf(G4[3].x * TB3.x, hB, FB[3].x); FB[3].y = fmaf(G4[3].y * TB3.y, hB, FB[3].y);
        FB[3].z = fmaf(G4[3].z * TB3.z, hB, FB[3].z); FB[3].w = fmaf(G4[3].w * TB3.w, hB, FB[3].w);
    }

    // ---- epilogue ----
    {
        float4* oA = reinterpret_cast<float4*>(out + 12288 + ((size_t)bA * HH + r) * FWID);
        float4* oB = reinterpret_cast<float4*>(out + 12288 + ((size_t)bB * HH + r) * FWID);
#pragma unroll
        for (int k = 0; k < 4; ++k) { oA[k * 32 + i] = FA[k]; oB[k * 32 + i] = FB[k]; }
    }
    if (i == 0) {
        out[4096 + (size_t)bA * HH + r] = hlA;
        out[4096 + (size_t)bB * HH + r] = hlB;
    }

    // tag_space: compute waves of slice-0 blocks; gatherers flagged TT+1
    if (sl == 0) {
        while (__hip_atomic_load(&lflag[0][0], __ATOMIC_ACQUIRE, __HIP_MEMORY_SCOPE_WORKGROUP) <= TT) {}
        while (__hip_atomic_load(&lflag[1][0], __ATOMIC_ACQUIRE, __HIP_MEMORY_SCOPE_WORKGROUP) <= TT) {}
        if (tid < 2 * OO) {
            const int bt = tid >> 7;
            const int o  = tid & 127;
            const float* hv = lh[bt][0];
            float acc = bout[o];
            const float* wo = wout + (size_t)o * HH;
#pragma unroll 4
            for (int jj = 0; jj < HH; ++jj) acc = fmaf(wo[jj], hv[jj], acc);
            out[(size_t)(bt ? bB : bA) * OO + o] = acc;
        }
    }
}

extern "C" void kernel_launch(void* const* d_in, const int* in_sizes, int n_in,
                              void* d_out, int out_size, void* d_ws, size_t ws_size,
                              hipStream_t stream) {
    (void)in_sizes; (void)n_in; (void)out_size; (void)ws_size;
    const float* x    = (const float*)d_in[0];
    const float* wlam = (const float*)d_in[1];
    const float* wgam = (const float*)d_in[2];
    const float* w    = (const float*)d_in[3];
    const float* bias = (const float*)d_in[4];
    const float* wout = (const float*)d_in[5];
    const float* bout = (const float*)d_in[6];
    float* out = (float*)d_out;

    u64* slots = (u64*)d_ws;

    // stamp 0 + h = 0.0 is exactly what step 0 consumes
    hipMemsetAsync(d_ws, 0, 2ull * BB * HH * 8ull, stream);

    void* args[] = {(void*)&x, (void*)&wlam, (void*)&wgam, (void*)&w, (void*)&bias,
                    (void*)&wout, (void*)&bout, (void*)&out, (void*)&slots};
    hipLaunchCooperativeKernel((void*)stpn_kernel, dim3(256), dim3(640), args, 0, stream);
}

// Round 12
// 285.818 us; speedup vs baseline: 3.3535x; 3.3535x over previous
//
#include <hip/hip_runtime.h>

#define BB 32
#define TT 128
#define II 256
#define HH 256
#define OO 128
#define FWID 512  // H + I

// d_ws: u64 slots[2][BB][HH] (parity, batch, row) = 128 KB.
// Slot = (stamp<<32)|float_bits(h); step s consumes stamp>=s from parity s&1,
// publishes stamp s+1 into parity (s+1)&1. Agent-scope relaxed (no fences);
// protocol proven on HW in R2/R3/R5/R8.
// Overwrite safety: producer writes stamp s+2 (same parity slot as stamp s)
// only in step s+1, gated on its block's gather(s+1) = all 256 rows at stamp
// s+1 = every block of this batch exited its stamp-s gather loop (all stamp-s
// reads complete). u64 atomics cannot tear.
//
// R12 vs R8 (258 us): one batch per block (256 blocks = 32 batches x 8
// slices), 16-lane rows, 32 rows/block. Halves per-batch publisher fan-out
// (16->8 blocks: smaller straggler max, half the poll waves/batch) and cuts
// all cross-lane reduces 5->4 levels. One exchange chain per block (R10's
// two-chain SIMD collision does not apply: still 8 waves/CU). Gatherer =
// wave 0 polling AFTER Phase P (R8-proven); dedicated gatherers (R6/R11)
// and sentinel indirection (R7) are measured dead ends.

typedef unsigned long long u64;

__device__ __forceinline__ u64 slot_ld(const u64* p) {
    return __hip_atomic_load(p, __ATOMIC_RELAXED, __HIP_MEMORY_SCOPE_AGENT);
}

// One wave gathers 256 rows of one batch (4 slots/lane, issued concurrently),
// stages h to LDS (ds_write_b128), release-stores an LDS flag.
__device__ __forceinline__ void gather_to_lds(const u64* base, int lane, unsigned us,
                                              float* dst, int* flag, int fval) {
    const u64* p = base + 4 * lane;
    u64 a, b, c, d;
    for (;;) {
        a = slot_ld(p);
        b = slot_ld(p + 1);
        c = slot_ld(p + 2);
        d = slot_ld(p + 3);
        bool ok = ((unsigned)(a >> 32) >= us) & ((unsigned)(b >> 32) >= us) &
                  ((unsigned)(c >> 32) >= us) & ((unsigned)(d >> 32) >= us);
        if (__all(ok)) break;
    }
    float4 hv;
    hv.x = __uint_as_float((unsigned)a);
    hv.y = __uint_as_float((unsigned)b);
    hv.z = __uint_as_float((unsigned)c);
    hv.w = __uint_as_float((unsigned)d);
    *reinterpret_cast<float4*>(dst + 4 * lane) = hv;
    if (lane == 0)  // release drains the wave's ds_write before the flag
        __hip_atomic_store(flag, fval, __ATOMIC_RELEASE, __HIP_MEMORY_SCOPE_WORKGROUP);
}

__global__ __launch_bounds__(512, 2)
void stpn_kernel(const float* __restrict__ x,      // (B,T,I)
                 const float* __restrict__ wlam,   // (H,FWID)
                 const float* __restrict__ wgam,   // (H,FWID)
                 const float* __restrict__ w,      // (H,FWID)
                 const float* __restrict__ bias,   // (H)
                 const float* __restrict__ wout,   // (O,H)
                 const float* __restrict__ bout,   // (O)
                 float* __restrict__ out,          // tag(4096) | h_T(8192) | F_T
                 u64* __restrict__ slots)
{
    __shared__ __align__(16) float lh[2][HH];      // [parity][row]
    __shared__ int lflag[2];                       // [parity]

    const int tid  = threadIdx.x;
    const int bk   = blockIdx.x;
    const int b    = bk & 31;        // batch
    const int sl   = bk >> 5;        // row slice 0..7 (32 rows each)
    const int wv   = tid >> 6;       // 0..7
    const int lane = tid & 63;
    const int g    = tid >> 4;       // 16-lane group 0..31 == row-within-slice
    const int i    = tid & 15;       // lane within group
    const int r    = sl * 32 + (g & 31);

    if (tid < 2) lflag[tid] = 0;

    // Per-lane f-chunks of row r: f = 64*k + 4*i + c, k=0..7 (k<4 x-part, k>=4 h-part)
    float4 W4[8], L4[8], G4[8], F4[8];
    {
        const float4* wr = reinterpret_cast<const float4*>(w    + (size_t)r * FWID);
        const float4* lr = reinterpret_cast<const float4*>(wlam + (size_t)r * FWID);
        const float4* gr = reinterpret_cast<const float4*>(wgam + (size_t)r * FWID);
#pragma unroll
        for (int k = 0; k < 8; ++k) {
            W4[k] = wr[k * 16 + i];
            L4[k] = lr[k * 16 + i];
            G4[k] = gr[k * 16 + i];
            F4[k] = make_float4(0.f, 0.f, 0.f, 0.f);
        }
    }
    const float bj = bias[r];
    float hl = 0.f;

    __syncthreads();   // lflag init visible

    for (int s = 0; s < TT; ++s) {
        const int par = s & 1;

        // x load (L2-resident after first pass): T[0..3] = x fragment
        const float4* xb = reinterpret_cast<const float4*>(x + ((size_t)b * TT + s) * II);
        float4 T0 = xb[i], T1 = xb[16 + i], T2 = xb[32 + i], T3 = xb[48 + i];

        // ---- Phase P: independent of h(s), runs before the gather ----
        float4 tw[4];                      // h-part tw, kept for dot_h
        float4 dx4 = make_float4(0,0,0,0), nv4 = make_float4(0,0,0,0);
        {
            float4 t;
            t.x = W4[0].x + F4[0].x; t.y = W4[0].y + F4[0].y; t.z = W4[0].z + F4[0].z; t.w = W4[0].w + F4[0].w;
            dx4.x = fmaf(T0.x, t.x, dx4.x); dx4.y = fmaf(T0.y, t.y, dx4.y);
            dx4.z = fmaf(T0.z, t.z, dx4.z); dx4.w = fmaf(T0.w, t.w, dx4.w);
            nv4.x = fmaf(t.x, t.x, nv4.x); nv4.y = fmaf(t.y, t.y, nv4.y);
            nv4.z = fmaf(t.z, t.z, nv4.z); nv4.w = fmaf(t.w, t.w, nv4.w);
            t.x = W4[1].x + F4[1].x; t.y = W4[1].y + F4[1].y; t.z = W4[1].z + F4[1].z; t.w = W4[1].w + F4[1].w;
            dx4.x = fmaf(T1.x, t.x, dx4.x); dx4.y = fmaf(T1.y, t.y, dx4.y);
            dx4.z = fmaf(T1.z, t.z, dx4.z); dx4.w = fmaf(T1.w, t.w, dx4.w);
            nv4.x = fmaf(t.x, t.x, nv4.x); nv4.y = fmaf(t.y, t.y, nv4.y);
            nv4.z = fmaf(t.z, t.z, nv4.z); nv4.w = fmaf(t.w, t.w, nv4.w);
            t.x = W4[2].x + F4[2].x; t.y = W4[2].y + F4[2].y; t.z = W4[2].z + F4[2].z; t.w = W4[2].w + F4[2].w;
            dx4.x = fmaf(T2.x, t.x, dx4.x); dx4.y = fmaf(T2.y, t.y, dx4.y);
            dx4.z = fmaf(T2.z, t.z, dx4.z); dx4.w = fmaf(T2.w, t.w, dx4.w);
            nv4.x = fmaf(t.x, t.x, nv4.x); nv4.y = fmaf(t.y, t.y, nv4.y);
            nv4.z = fmaf(t.z, t.z, nv4.z); nv4.w = fmaf(t.w, t.w, nv4.w);
            t.x = W4[3].x + F4[3].x; t.y = W4[3].y + F4[3].y; t.z = W4[3].z + F4[3].z; t.w = W4[3].w + F4[3].w;
            dx4.x = fmaf(T3.x, t.x, dx4.x); dx4.y = fmaf(T3.y, t.y, dx4.y);
            dx4.z = fmaf(T3.z, t.z, dx4.z); dx4.w = fmaf(T3.w, t.w, dx4.w);
            nv4.x = fmaf(t.x, t.x, nv4.x); nv4.y = fmaf(t.y, t.y, nv4.y);
            nv4.z = fmaf(t.z, t.z, nv4.z); nv4.w = fmaf(t.w, t.w, nv4.w);
#pragma unroll
            for (int k = 0; k < 4; ++k) {
                tw[k].x = W4[k + 4].x + F4[k + 4].x; tw[k].y = W4[k + 4].y + F4[k + 4].y;
                tw[k].z = W4[k + 4].z + F4[k + 4].z; tw[k].w = W4[k + 4].w + F4[k + 4].w;
                nv4.x = fmaf(tw[k].x, tw[k].x, nv4.x); nv4.y = fmaf(tw[k].y, tw[k].y, nv4.y);
                nv4.z = fmaf(tw[k].z, tw[k].z, nv4.z); nv4.w = fmaf(tw[k].w, tw[k].w, nv4.w);
            }
        }
        float dxs = (dx4.x + dx4.y) + (dx4.z + dx4.w);
        float nrm = (nv4.x + nv4.y) + (nv4.z + nv4.w);
#pragma unroll
        for (int off = 1; off <= 8; off <<= 1) {   // 4-level reduce over 16-lane row
            dxs += __shfl_xor(dxs, off, 64);
            nrm += __shfl_xor(nrm, off, 64);
        }
        const float invn = 1.0f / (sqrtf(nrm) + 1e-16f);

        // F decay + gamma*x (h-independent)
#pragma unroll
        for (int k = 0; k < 8; ++k) {
            F4[k].x = L4[k].x * (F4[k].x * invn); F4[k].y = L4[k].y * (F4[k].y * invn);
            F4[k].z = L4[k].z * (F4[k].z * invn); F4[k].w = L4[k].w * (F4[k].w * invn);
        }
        T0.x *= G4[0].x; T0.y *= G4[0].y; T0.z *= G4[0].z; T0.w *= G4[0].w;
        T1.x *= G4[1].x; T1.y *= G4[1].y; T1.z *= G4[1].z; T1.w *= G4[1].w;
        T2.x *= G4[2].x; T2.y *= G4[2].y; T2.z *= G4[2].z; T2.w *= G4[2].w;
        T3.x *= G4[3].x; T3.y *= G4[3].y; T3.z *= G4[3].z; T3.w *= G4[3].w;

        // ---- gather (wave 0, pipelined after Phase P) ----
        if (wv == 0) {
            gather_to_lds(slots + ((size_t)par * BB + b) * HH, lane,
                          (unsigned)s, lh[par], &lflag[par], s + 1);
        }

        // ---- Phase W: LDS flag spin, consume h ----
        while (__hip_atomic_load(&lflag[par], __ATOMIC_ACQUIRE, __HIP_MEMORY_SCOPE_WORKGROUP) <= s) {}
        const float4* lh4 = reinterpret_cast<const float4*>(lh[par]);
        float4 H0 = lh4[i], H1 = lh4[16 + i], H2 = lh4[32 + i], H3 = lh4[48 + i];

        // dot_h: 4 independent component chains + tree combine (short dep depth)
        float4 a4;
        a4.x = H0.x * tw[0].x; a4.y = H0.y * tw[0].y; a4.z = H0.z * tw[0].z; a4.w = H0.w * tw[0].w;
        a4.x = fmaf(H1.x, tw[1].x, a4.x); a4.y = fmaf(H1.y, tw[1].y, a4.y);
        a4.z = fmaf(H1.z, tw[1].z, a4.z); a4.w = fmaf(H1.w, tw[1].w, a4.w);
        a4.x = fmaf(H2.x, tw[2].x, a4.x); a4.y = fmaf(H2.y, tw[2].y, a4.y);
        a4.z = fmaf(H2.z, tw[2].z, a4.z); a4.w = fmaf(H2.w, tw[2].w, a4.w);
        a4.x = fmaf(H3.x, tw[3].x, a4.x); a4.y = fmaf(H3.y, tw[3].y, a4.y);
        a4.z = fmaf(H3.z, tw[3].z, a4.z); a4.w = fmaf(H3.w, tw[3].w, a4.w);
        float dh = (a4.x + a4.y) + (a4.z + a4.w);
#pragma unroll
        for (int off = 1; off <= 8; off <<= 1) dh += __shfl_xor(dh, off, 64);

        const float e = __expf(2.0f * (dxs + dh + bj));
        const float h = (1.0f - 2.0f / (e + 1.0f)) * invn;
        hl = h;

        // publish ASAP (relaxed agent store, no fence)
        if (i == 0) {
            __hip_atomic_store(slots + ((size_t)(par ^ 1) * BB + b) * HH + r,
                               ((u64)(unsigned)(s + 1) << 32) | (unsigned)__float_as_uint(h),
                               __ATOMIC_RELAXED, __HIP_MEMORY_SCOPE_AGENT);
        }

        // ---- Phase U: F += (gamma*t)*h ----
        F4[0].x = fmaf(T0.x, h, F4[0].x); F4[0].y = fmaf(T0.y, h, F4[0].y);
        F4[0].z = fmaf(T0.z, h, F4[0].z); F4[0].w = fmaf(T0.w, h, F4[0].w);
        F4[1].x = fmaf(T1.x, h, F4[1].x); F4[1].y = fmaf(T1.y, h, F4[1].y);
        F4[1].z = fmaf(T1.z, h, F4[1].z); F4[1].w = fmaf(T1.w, h, F4[1].w);
        F4[2].x = fmaf(T2.x, h, F4[2].x); F4[2].y = fmaf(T2.y, h, F4[2].y);
        F4[2].z = fmaf(T2.z, h, F4[2].z); F4[2].w = fmaf(T2.w, h, F4[2].w);
        F4[3].x = fmaf(T3.x, h, F4[3].x); F4[3].y = fmaf(T3.y, h, F4[3].y);
        F4[3].z = fmaf(T3.z, h, F4[3].z); F4[3].w = fmaf(T3.w, h, F4[3].w);
        F4[4].x = fmaf(G4[4].x * H0.x, h, F4[4].x); F4[4].y = fmaf(G4[4].y * H0.y, h, F4[4].y);
        F4[4].z = fmaf(G4[4].z * H0.z, h, F4[4].z); F4[4].w = fmaf(G4[4].w * H0.w, h, F4[4].w);
        F4[5].x = fmaf(G4[5].x * H1.x, h, F4[5].x); F4[5].y = fmaf(G4[5].y * H1.y, h, F4[5].y);
        F4[5].z = fmaf(G4[5].z * H1.z, h, F4[5].z); F4[5].w = fmaf(G4[5].w * H1.w, h, F4[5].w);
        F4[6].x = fmaf(G4[6].x * H2.x, h, F4[6].x); F4[6].y = fmaf(G4[6].y * H2.y, h, F4[6].y);
        F4[6].z = fmaf(G4[6].z * H2.z, h, F4[6].z); F4[6].w = fmaf(G4[6].w * H2.w, h, F4[6].w);
        F4[7].x = fmaf(G4[7].x * H3.x, h, F4[7].x); F4[7].y = fmaf(G4[7].y * H3.y, h, F4[7].y);
        F4[7].z = fmaf(G4[7].z * H3.z, h, F4[7].z); F4[7].w = fmaf(G4[7].w * H3.w, h, F4[7].w);
    }

    // ---- epilogue: F_T, h_T ----
    {
        float4* fo = reinterpret_cast<float4*>(out + 12288 + ((size_t)b * HH + r) * FWID);
#pragma unroll
        for (int k = 0; k < 8; ++k) fo[k * 16 + i] = F4[k];
    }
    if (i == 0) out[4096 + (size_t)b * HH + r] = hl;

    // tag_space: sl==0 blocks (one per batch) gather final h (stamp TT, parity 0)
    if (sl == 0) {
        if (wv == 0) {
            gather_to_lds(slots + ((size_t)(TT & 1) * BB + b) * HH, lane,
                          (unsigned)TT, lh[0], &lflag[0], TT + 1);
        }
        while (__hip_atomic_load(&lflag[0], __ATOMIC_ACQUIRE, __HIP_MEMORY_SCOPE_WORKGROUP) <= TT) {}
        if (tid < OO) {
            const float* hv = lh[0];
            float acc = bout[tid];
            const float* wo = wout + (size_t)tid * HH;
#pragma unroll 4
            for (int jj = 0; jj < HH; ++jj) acc = fmaf(wo[jj], hv[jj], acc);
            out[(size_t)b * OO + tid] = acc;
        }
    }
}

extern "C" void kernel_launch(void* const* d_in, const int* in_sizes, int n_in,
                              void* d_out, int out_size, void* d_ws, size_t ws_size,
                              hipStream_t stream) {
    (void)in_sizes; (void)n_in; (void)out_size; (void)ws_size;
    const float* x    = (const float*)d_in[0];
    const float* wlam = (const float*)d_in[1];
    const float* wgam = (const float*)d_in[2];
    const float* w    = (const float*)d_in[3];
    const float* bias = (const float*)d_in[4];
    const float* wout = (const float*)d_in[5];
    const float* bout = (const float*)d_in[6];
    float* out = (float*)d_out;

    u64* slots = (u64*)d_ws;

    // stamp 0 + h = 0.0 is exactly what step 0 consumes
    hipMemsetAsync(d_ws, 0, 2ull * BB * HH * 8ull, stream);

    void* args[] = {(void*)&x, (void*)&wlam, (void*)&wgam, (void*)&w, (void*)&bias,
                    (void*)&wout, (void*)&bout, (void*)&out, (void*)&slots};
    hipLaunchCooperativeKernel((void*)stpn_kernel, dim3(256), dim3(512), args, 0, stream);
}